// Round 10
// baseline (152.738 us; speedup 1.0000x reference)
//
#include <hip/hip_runtime.h>
#include <math.h>

#define SIGMA_BOOST 2.0f
#define EPSILON 1e-6f

// native clang vector type
typedef float vfloat4 __attribute__((ext_vector_type(4)));

// ---------------------------------------------------------------------------
// Pre-pass: per-t parameters -> float4 {mean_row, mean_col, sigma, pvalue}
//   mean  = sigmoid(pmean) * (N-1)
//   sigma = (softplus(psigma + SIGMA_BOOST) + EPS) * N
// ---------------------------------------------------------------------------
__global__ void params_kernel(const float2* __restrict__ pmeans,
                              const float* __restrict__ psigmas,
                              const float* __restrict__ pvalues,
                              float4* __restrict__ params, int N) {
    int t = blockIdx.x * blockDim.x + threadIdx.x;
    if (t >= N) return;
    float2 pm = pmeans[t];
    float scale = (float)(N - 1);
    float m0 = __fmul_rn(__fdiv_rn(1.0f, __fadd_rn(1.0f, expf(-pm.x))), scale);
    float m1 = __fmul_rn(__fdiv_rn(1.0f, __fadd_rn(1.0f, expf(-pm.y))), scale);
    float z  = __fadd_rn(psigmas[t], SIGMA_BOOST);
    float sp = __fadd_rn(fmaxf(z, 0.0f), log1pf(expf(-fabsf(z))));
    float sg = __fmul_rn(__fadd_rn(sp, EPSILON), (float)N);
    params[t] = make_float4(m0, m1, sg, pvalues[t]);
}

// ---------------------------------------------------------------------------
// Round 10 — single-variable A/B vs the r7 champion (41 us):
// REMOVE the nontemporal hint from the noise stream loads. NT has been in
// every 41-us variant since r2 and was never isolated. On gfx950 NT loads
// bypass cache retention -> deep-memory latency (~900cy) on every noise
// load, which the in-order vmcnt forces every commit to expose. If NT was
// the limiter, dur drops to ~30 us and BW rises; if unchanged, NT is
// exonerated and the 2.2 TB/s mixed-access plateau is the next suspect.
// Everything else is bit-identical to the verified r7 kernel (2-deep
// software pipeline split at the gather, masked LDS atomics, 0/N-1 row
// peel into registers, NT write-out).
// ---------------------------------------------------------------------------
__device__ __forceinline__ void load_step(const vfloat4* __restrict__ nb4,
                                          const float4* __restrict__ params,
                                          int q, vfloat4& nz, float4& pA,
                                          float4& pB) {
    nz = nb4[q];                 // plain load (was __builtin_nontemporal_load)
    pA = params[2 * q];
    pB = params[2 * q + 1];
}

__device__ __forceinline__ void gather_step(const vfloat4 nz, const float4 pA,
                                            const float4 pB,
                                            const float* __restrict__ xb,
                                            const float fN1,
                                            int& r0, int& r1, float& w0,
                                            float& w1, float& xv0, float& xv1) {
    // sample = mean + sigma*noise, deliberately UNFUSED (match numpy rounding)
    float s0 = __fadd_rn(pA.x, __fmul_rn(pA.z, nz.x));
    float s1 = __fadd_rn(pA.y, __fmul_rn(pA.z, nz.y));
    float s2 = __fadd_rn(pB.x, __fmul_rn(pB.z, nz.z));
    float s3 = __fadd_rn(pB.y, __fmul_rn(pB.z, nz.w));
    // np.round = half-to-even = rintf; clamp in float, exact int cvt
    r0     = (int)fminf(fmaxf(rintf(s0), 0.0f), fN1);
    int c0 = (int)fminf(fmaxf(rintf(s1), 0.0f), fN1);
    r1     = (int)fminf(fmaxf(rintf(s2), 0.0f), fN1);
    int c1 = (int)fminf(fmaxf(rintf(s3), 0.0f), fN1);
    w0 = pA.w; w1 = pB.w;
    xv0 = xb[c0];                 // unconditional gathers (hot lines are ~free)
    xv1 = xb[c1];
}

__device__ __forceinline__ void commit_step(float* __restrict__ ly,
                                            const int iN1, int r0, int r1,
                                            float w0, float w1, float xv0,
                                            float xv1, float& acc0,
                                            float& accE) {
    float ctr0 = __fmul_rn(w0, xv0);
    float ctr1 = __fmul_rn(w1, xv1);
    bool lo0 = (r0 == 0), hi0 = (r0 == iN1);
    bool lo1 = (r1 == 0), hi1 = (r1 == iN1);
    if (!(lo0 | hi0)) atomicAdd(&ly[r0], ctr0);   // ~20% of lanes active
    if (!(lo1 | hi1)) atomicAdd(&ly[r1], ctr1);
    acc0 = __fadd_rn(acc0, lo0 ? ctr0 : 0.0f);    // cndmask, branchless
    accE = __fadd_rn(accE, hi0 ? ctr0 : 0.0f);
    acc0 = __fadd_rn(acc0, lo1 ? ctr1 : 0.0f);
    accE = __fadd_rn(accE, hi1 ? ctr1 : 0.0f);
}

// ---------------------------------------------------------------------------
// One block per batch row. 64 KB LDS y-row accumulator; 2 blocks/CU.
// ---------------------------------------------------------------------------
template <bool INLINE_PARAMS>
__launch_bounds__(1024, 8)
__global__ void contract_kernel(const float* __restrict__ x,
                                const float2* __restrict__ noise,
                                const float4* __restrict__ params,
                                const float2* __restrict__ pmeans,
                                const float* __restrict__ psigmas,
                                const float* __restrict__ pvalues,
                                float* __restrict__ y, int N) {
    extern __shared__ float ly[];
    const int b = blockIdx.x;
    const int tid = threadIdx.x;
    const int nthr = blockDim.x;

    // zero LDS accumulator (vectorized)
    float4* ly4 = (float4*)ly;
    const int n4 = N >> 2;
    for (int i = tid; i < n4; i += nthr) ly4[i] = make_float4(0.f, 0.f, 0.f, 0.f);
    __syncthreads();

    const float* xb = x + (size_t)b * N;
    const float fN1 = (float)(N - 1);
    const int iN1 = N - 1;
    float acc0 = 0.0f, accE = 0.0f;

    const int steps = ((N >> 1) % nthr == 0) ? (N >> 1) / nthr : 0;

    if (!INLINE_PARAMS && steps >= 2 && (steps % 2) == 0) {
        // ---- 2-deep software pipeline, 2 samples per step ------------------
        const vfloat4* nb4 = (const vfloat4*)(noise + (size_t)b * N); // N/2 vecs

        vfloat4 nzA, nzB;
        float4 paA, pbA, paB, pbB;
        int   r0A, r1A, r0B, r1B;
        float w0A, w1A, w0B, w1B;
        float x0A, x1A, x0B, x1B;

        // prologue: loads for steps 0 and 1; gathers for step 0
        load_step(nb4, params, 0 * nthr + tid, nzA, paA, pbA);
        load_step(nb4, params, 1 * nthr + tid, nzB, paB, pbB);
        gather_step(nzA, paA, pbA, xb, fN1, r0A, r1A, w0A, w1A, x0A, x1A);

        for (int s = 0; s < steps; s += 2) {
            if (s + 2 < steps)
                load_step(nb4, params, (s + 2) * nthr + tid, nzA, paA, pbA);
            gather_step(nzB, paB, pbB, xb, fN1, r0B, r1B, w0B, w1B, x0B, x1B);
            commit_step(ly, iN1, r0A, r1A, w0A, w1A, x0A, x1A, acc0, accE);
            if (s + 3 < steps)
                load_step(nb4, params, (s + 3) * nthr + tid, nzB, paB, pbB);
            if (s + 2 < steps)
                gather_step(nzA, paA, pbA, xb, fN1, r0A, r1A, w0A, w1A, x0A, x1A);
            commit_step(ly, iN1, r0B, r1B, w0B, w1B, x0B, x1B, acc0, accE);
        }
    } else {
        // ---- generic / inline-params fallback (round-6 masked body) --------
        const float2* nb = noise + (size_t)b * N;
        for (int t = tid; t < N; t += nthr) {
            float4 p;
            if (INLINE_PARAMS) {
                float2 pm = pmeans[t];
                float scale = (float)(N - 1);
                p.x = __fmul_rn(__fdiv_rn(1.0f, __fadd_rn(1.0f, expf(-pm.x))), scale);
                p.y = __fmul_rn(__fdiv_rn(1.0f, __fadd_rn(1.0f, expf(-pm.y))), scale);
                float z  = __fadd_rn(psigmas[t], SIGMA_BOOST);
                float sp = __fadd_rn(fmaxf(z, 0.0f), log1pf(expf(-fabsf(z))));
                p.z = __fmul_rn(__fadd_rn(sp, EPSILON), (float)N);
                p.w = pvalues[t];
            } else {
                p = params[t];
            }
            float2 nz = nb[t];
            float s0 = __fadd_rn(p.x, __fmul_rn(p.z, nz.x));
            float s1 = __fadd_rn(p.y, __fmul_rn(p.z, nz.y));
            int row = (int)fminf(fmaxf(rintf(s0), 0.0f), fN1);
            int col = (int)fminf(fmaxf(rintf(s1), 0.0f), fN1);
            float xv = xb[col];
            float ctr = __fmul_rn(p.w, xv);
            bool lo = (row == 0);
            bool hi = (row == iN1);
            if (!(lo | hi)) atomicAdd(&ly[row], ctr);
            acc0 = __fadd_rn(acc0, lo ? ctr : 0.0f);
            accE = __fadd_rn(accE, hi ? ctr : 0.0f);
        }
    }

    // fold register accumulators: wave shfl-reduce, one atomic per wave
    for (int off = 32; off > 0; off >>= 1) {
        acc0 = __fadd_rn(acc0, __shfl_down(acc0, off, 64));
        accE = __fadd_rn(accE, __shfl_down(accE, off, 64));
    }
    if ((tid & 63) == 0) {
        atomicAdd(&ly[0], acc0);
        atomicAdd(&ly[iN1], accE);
    }
    __syncthreads();

    // coalesced nontemporal write-out of the full row (y is never re-read)
    const vfloat4* lv4 = (const vfloat4*)ly;
    vfloat4* yb4 = (vfloat4*)(y + (size_t)b * N);
    for (int i = tid; i < n4; i += nthr)
        __builtin_nontemporal_store(lv4[i], &yb4[i]);
}

extern "C" void kernel_launch(void* const* d_in, const int* in_sizes, int n_in,
                              void* d_out, int out_size, void* d_ws, size_t ws_size,
                              hipStream_t stream) {
    const float*  x       = (const float*)d_in[0];
    const float2* noise   = (const float2*)d_in[1];
    const float2* pmeans  = (const float2*)d_in[2];
    const float*  psigmas = (const float*)d_in[3];
    const float*  pvalues = (const float*)d_in[4];
    float* y = (float*)d_out;

    const int N = in_sizes[3];          // psigmas is (N,)
    const int B = in_sizes[0] / N;      // x is (B,N)

    const size_t params_bytes = (size_t)N * sizeof(float4);
    const bool use_ws = (ws_size >= params_bytes) && (d_ws != nullptr);

    const int block = 1024;
    const size_t lds_bytes = (size_t)N * sizeof(float);  // 64 KB at N=16384

    if (use_ws) {
        float4* params = (float4*)d_ws;
        params_kernel<<<(N + 255) / 256, 256, 0, stream>>>(pmeans, psigmas,
                                                           pvalues, params, N);
        contract_kernel<false><<<B, block, lds_bytes, stream>>>(
            x, noise, params, nullptr, nullptr, nullptr, y, N);
    } else {
        contract_kernel<true><<<B, block, lds_bytes, stream>>>(
            x, noise, nullptr, pmeans, psigmas, pvalues, y, N);
    }
}

// Round 12
// 149.204 us; speedup vs baseline: 1.0237x; 1.0237x over previous
//
#include <hip/hip_runtime.h>
#include <math.h>

#define SIGMA_BOOST 2.0f
#define EPSILON 1e-6f

// native clang vector type (required for nontemporal builtins and "+v" pins)
typedef float vfloat4 __attribute__((ext_vector_type(4)));

// Rule-#17 value pin: forces the value to be materialized in VGPRs at this
// program point — the producing load cannot be sunk past it. Zero cost.
#define PIN4(v)  asm volatile("" : "+v"(v))
#define PIN1(v)  asm volatile("" : "+v"(v))

// ---------------------------------------------------------------------------
// Pre-pass: per-t parameters -> float4 {mean_row, mean_col, sigma, pvalue}
//   mean  = sigmoid(pmean) * (N-1)
//   sigma = (softplus(psigma + SIGMA_BOOST) + EPS) * N
// ---------------------------------------------------------------------------
__global__ void params_kernel(const float2* __restrict__ pmeans,
                              const float* __restrict__ psigmas,
                              const float* __restrict__ pvalues,
                              float4* __restrict__ params, int N) {
    int t = blockIdx.x * blockDim.x + threadIdx.x;
    if (t >= N) return;
    float2 pm = pmeans[t];
    float scale = (float)(N - 1);
    float m0 = __fmul_rn(__fdiv_rn(1.0f, __fadd_rn(1.0f, expf(-pm.x))), scale);
    float m1 = __fmul_rn(__fdiv_rn(1.0f, __fadd_rn(1.0f, expf(-pm.y))), scale);
    float z  = __fadd_rn(psigmas[t], SIGMA_BOOST);
    float sp = __fadd_rn(fmaxf(z, 0.0f), log1pf(expf(-fabsf(z))));
    float sg = __fmul_rn(__fadd_rn(sp, EPSILON), (float)N);
    params[t] = make_float4(m0, m1, sg, pvalues[t]);
}

// ---------------------------------------------------------------------------
// Round 12 — r6's verified body + empty-asm value pins to FORCE the pipeline.
// History: r4-r11 all failed the same way — hipcc sinks prefetch loads back
// to their uses at IR level (VGPR stuck 20-32), exposing one NT-HBM/L2
// round-trip per 2-sample step. asm-load variants (r9/r11) pin issue order
// but hit register-allocation hazards (allocator copies an async "=v" dest
// before the data lands -> r11's wrong results). The pin trick keeps all
// register management and waitcnt counting in the compiler (hazard-free)
// while making sinking impossible:
//   zone A: compute indices from CURRENT regs, issue both gathers, PIN xv
//   zone B: issue NEXT step's noise (nt) + params loads, PIN them
//   zone C: commit (masked LDS atomic + 0/N-1 register peel)
// Issue order old->young = {gathers, prefetches}: the commit's auto wait is
// vmcnt(3) (prefetches stay in flight); next iteration's first use retires
// iteration-old prefetches. Numerics bit-identical to the verified kernels.
// ---------------------------------------------------------------------------
template <bool INLINE_PARAMS>
__launch_bounds__(1024, 8)
__global__ void contract_kernel(const float* __restrict__ x,
                                const float2* __restrict__ noise,
                                const float4* __restrict__ params,
                                const float2* __restrict__ pmeans,
                                const float* __restrict__ psigmas,
                                const float* __restrict__ pvalues,
                                float* __restrict__ y, int N) {
    extern __shared__ float ly[];
    const int b = blockIdx.x;
    const int tid = threadIdx.x;
    const int nthr = blockDim.x;

    // zero LDS accumulator (vectorized)
    float4* ly4 = (float4*)ly;
    const int n4 = N >> 2;
    for (int i = tid; i < n4; i += nthr) ly4[i] = make_float4(0.f, 0.f, 0.f, 0.f);
    __syncthreads();

    const float* xb = x + (size_t)b * N;
    const float fN1 = (float)(N - 1);
    const int iN1 = N - 1;
    float acc0 = 0.0f, accE = 0.0f;

    const int steps = ((N >> 1) % nthr == 0) ? (N >> 1) / nthr : 0;

    if (!INLINE_PARAMS && steps >= 2) {
        const vfloat4* nb4 = (const vfloat4*)(noise + (size_t)b * N); // N/2 vecs
        const vfloat4* pp  = (const vfloat4*)params;

        // ---- prologue: load step 0's set, pin it ---------------------------
        int q = tid;
        vfloat4 nz = __builtin_nontemporal_load(&nb4[q]);
        vfloat4 pa = pp[2 * q];
        vfloat4 pb = pp[2 * q + 1];
        PIN4(nz); PIN4(pa); PIN4(pb);

        for (int s = 0; s < steps; ++s) {
            // ---- zone A: compute indices, issue gathers, pin ----------------
            // sample = mean + sigma*noise, deliberately UNFUSED (numpy match)
            float s0 = __fadd_rn(pa.x, __fmul_rn(pa.z, nz.x));
            float s1 = __fadd_rn(pa.y, __fmul_rn(pa.z, nz.y));
            float s2 = __fadd_rn(pb.x, __fmul_rn(pb.z, nz.z));
            float s3 = __fadd_rn(pb.y, __fmul_rn(pb.z, nz.w));
            // np.round = half-to-even = rintf; clamp in float, exact int cvt
            int r0 = (int)fminf(fmaxf(rintf(s0), 0.0f), fN1);
            int c0 = (int)fminf(fmaxf(rintf(s1), 0.0f), fN1);
            int r1 = (int)fminf(fmaxf(rintf(s2), 0.0f), fN1);
            int c1 = (int)fminf(fmaxf(rintf(s3), 0.0f), fN1);
            float w0 = pa.w, w1 = pb.w;
            float xv0 = xb[c0];             // gathers issue here (oldest)
            float xv1 = xb[c1];
            PIN1(xv0); PIN1(xv1);           // loads may not sink past this

            // ---- zone B: prefetch next step's set, pin ----------------------
            vfloat4 nzn, pan, pbn;
            bool have_next = (s + 1 < steps);
            if (have_next) {                // uniform branch
                int qn = q + nthr;
                nzn = __builtin_nontemporal_load(&nb4[qn]);
                pan = pp[2 * qn];
                pbn = pp[2 * qn + 1];
                PIN4(nzn); PIN4(pan); PIN4(pbn);  // issued before commit waits
                q = qn;
            }

            // ---- zone C: commit (wait vmcnt(3): prefetches stay in flight) --
            float ctr0 = __fmul_rn(w0, xv0);
            float ctr1 = __fmul_rn(w1, xv1);
            bool lo0 = (r0 == 0), hi0 = (r0 == iN1);
            bool lo1 = (r1 == 0), hi1 = (r1 == iN1);
            if (!(lo0 | hi0)) atomicAdd(&ly[r0], ctr0);   // ~20% lanes active
            if (!(lo1 | hi1)) atomicAdd(&ly[r1], ctr1);
            acc0 = __fadd_rn(acc0, lo0 ? ctr0 : 0.0f);    // cndmask, branchless
            accE = __fadd_rn(accE, hi0 ? ctr0 : 0.0f);
            acc0 = __fadd_rn(acc0, lo1 ? ctr1 : 0.0f);
            accE = __fadd_rn(accE, hi1 ? ctr1 : 0.0f);

            // rotate register sets (SSA rename, no copies emitted)
            if (have_next) { nz = nzn; pa = pan; pb = pbn; }
        }
    } else {
        // ---- generic / inline-params fallback (r6-verified masked body) ----
        const float2* nb = noise + (size_t)b * N;
        for (int t = tid; t < N; t += nthr) {
            float4 p;
            if (INLINE_PARAMS) {
                float2 pm = pmeans[t];
                float scale = (float)(N - 1);
                p.x = __fmul_rn(__fdiv_rn(1.0f, __fadd_rn(1.0f, expf(-pm.x))), scale);
                p.y = __fmul_rn(__fdiv_rn(1.0f, __fadd_rn(1.0f, expf(-pm.y))), scale);
                float z  = __fadd_rn(psigmas[t], SIGMA_BOOST);
                float sp = __fadd_rn(fmaxf(z, 0.0f), log1pf(expf(-fabsf(z))));
                p.z = __fmul_rn(__fadd_rn(sp, EPSILON), (float)N);
                p.w = pvalues[t];
            } else {
                p = params[t];
            }
            float2 nz = nb[t];
            float s0 = __fadd_rn(p.x, __fmul_rn(p.z, nz.x));
            float s1 = __fadd_rn(p.y, __fmul_rn(p.z, nz.y));
            int row = (int)fminf(fmaxf(rintf(s0), 0.0f), fN1);
            int col = (int)fminf(fmaxf(rintf(s1), 0.0f), fN1);
            float xv = xb[col];
            float ctr = __fmul_rn(p.w, xv);
            bool lo = (row == 0);
            bool hi = (row == iN1);
            if (!(lo | hi)) atomicAdd(&ly[row], ctr);
            acc0 = __fadd_rn(acc0, lo ? ctr : 0.0f);
            accE = __fadd_rn(accE, hi ? ctr : 0.0f);
        }
    }

    // fold register accumulators: wave shfl-reduce, one atomic per wave
    for (int off = 32; off > 0; off >>= 1) {
        acc0 = __fadd_rn(acc0, __shfl_down(acc0, off, 64));
        accE = __fadd_rn(accE, __shfl_down(accE, off, 64));
    }
    if ((tid & 63) == 0) {
        atomicAdd(&ly[0], acc0);
        atomicAdd(&ly[iN1], accE);
    }
    __syncthreads();

    // coalesced nontemporal write-out of the full row (y is never re-read)
    const vfloat4* lv4 = (const vfloat4*)ly;
    vfloat4* yb4 = (vfloat4*)(y + (size_t)b * N);
    for (int i = tid; i < n4; i += nthr)
        __builtin_nontemporal_store(lv4[i], &yb4[i]);
}

extern "C" void kernel_launch(void* const* d_in, const int* in_sizes, int n_in,
                              void* d_out, int out_size, void* d_ws, size_t ws_size,
                              hipStream_t stream) {
    const float*  x       = (const float*)d_in[0];
    const float2* noise   = (const float2*)d_in[1];
    const float2* pmeans  = (const float2*)d_in[2];
    const float*  psigmas = (const float*)d_in[3];
    const float*  pvalues = (const float*)d_in[4];
    float* y = (float*)d_out;

    const int N = in_sizes[3];          // psigmas is (N,)
    const int B = in_sizes[0] / N;      // x is (B,N)

    const size_t params_bytes = (size_t)N * sizeof(float4);
    const bool use_ws = (ws_size >= params_bytes) && (d_ws != nullptr);

    const int block = 1024;
    const size_t lds_bytes = (size_t)N * sizeof(float);  // 64 KB at N=16384

    if (use_ws) {
        float4* params = (float4*)d_ws;
        params_kernel<<<(N + 255) / 256, 256, 0, stream>>>(pmeans, psigmas,
                                                           pvalues, params, N);
        contract_kernel<false><<<B, block, lds_bytes, stream>>>(
            x, noise, params, nullptr, nullptr, nullptr, y, N);
    } else {
        contract_kernel<true><<<B, block, lds_bytes, stream>>>(
            x, noise, nullptr, pmeans, psigmas, pvalues, y, N);
    }
}

// Round 13
// 140.329 us; speedup vs baseline: 1.0884x; 1.0632x over previous
//
#include <hip/hip_runtime.h>
#include <math.h>

#define SIGMA_BOOST 2.0f
#define EPSILON 1e-6f

// native clang vector type (required for nontemporal builtins and "+v" pins)
typedef float vfloat4 __attribute__((ext_vector_type(4)));

// value pin: load feeding v cannot be sunk past this point (zero cost)
#define PIN4(v)  asm volatile("" : "+v"(v))

// ---------------------------------------------------------------------------
// Pre-pass: per-t parameters -> float4 {mean_row, mean_col, sigma, pvalue}
//   mean  = sigmoid(pmean) * (N-1)
//   sigma = (softplus(psigma + SIGMA_BOOST) + EPS) * N
// ---------------------------------------------------------------------------
__global__ void params_kernel(const float2* __restrict__ pmeans,
                              const float* __restrict__ psigmas,
                              const float* __restrict__ pvalues,
                              float4* __restrict__ params, int N) {
    int t = blockIdx.x * blockDim.x + threadIdx.x;
    if (t >= N) return;
    float2 pm = pmeans[t];
    float scale = (float)(N - 1);
    float m0 = __fmul_rn(__fdiv_rn(1.0f, __fadd_rn(1.0f, expf(-pm.x))), scale);
    float m1 = __fmul_rn(__fdiv_rn(1.0f, __fadd_rn(1.0f, expf(-pm.y))), scale);
    float z  = __fadd_rn(psigmas[t], SIGMA_BOOST);
    float sp = __fadd_rn(fmaxf(z, 0.0f), log1pf(expf(-fabsf(z))));
    float sg = __fmul_rn(__fadd_rn(sp, EPSILON), (float)N);
    params[t] = make_float4(m0, m1, sg, pvalues[t]);
}

// ---------------------------------------------------------------------------
// Round 13 — move the gather OFF the vmcnt counter (latency-domain fix).
// r4-r12 all land at 41-44 us because the x-gather is a vmem op issued and
// consumed within one step: the in-order vmcnt forces one full L2/L3
// round-trip per step (64 step-instances x ~1500cy = the observed ~100K cyc;
// issue work is only ~10K). This round: x-row AND y-row both in LDS (128 KB,
// 1 block/CU, 16 waves). The gather becomes ds_read_b32 (~120cy, lgkmcnt,
// 80% same-address broadcast = free). The commit never touches vmcnt, so the
// stream prefetch genuinely stays in flight across steps. vs r3 (which
// tested x+y-in-LDS at 65us): r3 had NO peel and all-64-lane serialized LDS
// atomics; here only ~13 lanes/wave atomic (masked) + 0/N-1 register peel.
// launch_bounds(1024,4): VGPR budget 128 removes the pressure that made
// hipcc sink every prefetch in r4-r12. Numerics bit-identical.
// ---------------------------------------------------------------------------
template <bool INLINE_PARAMS>
__launch_bounds__(1024, 4)
__global__ void contract_kernel(const float* __restrict__ x,
                                const float2* __restrict__ noise,
                                const float4* __restrict__ params,
                                const float2* __restrict__ pmeans,
                                const float* __restrict__ psigmas,
                                const float* __restrict__ pvalues,
                                float* __restrict__ y, int N) {
    extern __shared__ float lds[];
    float* ly = lds;          // N floats: y-row accumulator
    float* lx = lds + N;      // N floats: x-row copy (fast path only)
    const int b = blockIdx.x;
    const int tid = threadIdx.x;
    const int nthr = blockDim.x;

    const float* xb = x + (size_t)b * N;
    const float fN1 = (float)(N - 1);
    const int iN1 = N - 1;
    const int n4 = N >> 2;

    const int steps = ((N >> 1) % nthr == 0) ? (N >> 1) / nthr : 0;
    const bool fast = !INLINE_PARAMS && steps >= 2 && ((N & 3) == 0);

    // init LDS: zero ly; fast path also stages the x-row
    float4* ly4 = (float4*)ly;
    if (fast) {
        vfloat4* lx4 = (vfloat4*)lx;
        const vfloat4* xb4 = (const vfloat4*)xb;
        for (int i = tid; i < n4; i += nthr) {
            ly4[i] = make_float4(0.f, 0.f, 0.f, 0.f);
            lx4[i] = xb4[i];
        }
    } else {
        for (int i = tid; i < n4; i += nthr)
            ly4[i] = make_float4(0.f, 0.f, 0.f, 0.f);
    }
    __syncthreads();

    float acc0 = 0.0f, accE = 0.0f;

    if (fast) {
        const vfloat4* nb4 = (const vfloat4*)(noise + (size_t)b * N); // N/2 vecs
        const vfloat4* pp  = (const vfloat4*)params;

        // prologue: step 0's stream set, pinned
        int q = tid;
        vfloat4 nz = __builtin_nontemporal_load(&nb4[q]);
        vfloat4 pa = pp[2 * q];
        vfloat4 pb = pp[2 * q + 1];
        PIN4(nz); PIN4(pa); PIN4(pb);

        for (int s = 0; s < steps; ++s) {
            // ---- zone A: indices from current regs, gathers from LDS --------
            // sample = mean + sigma*noise, deliberately UNFUSED (numpy match)
            float s0 = __fadd_rn(pa.x, __fmul_rn(pa.z, nz.x));
            float s1 = __fadd_rn(pa.y, __fmul_rn(pa.z, nz.y));
            float s2 = __fadd_rn(pb.x, __fmul_rn(pb.z, nz.z));
            float s3 = __fadd_rn(pb.y, __fmul_rn(pb.z, nz.w));
            // np.round = half-to-even = rintf; clamp in float, exact int cvt
            int r0 = (int)fminf(fmaxf(rintf(s0), 0.0f), fN1);
            int c0 = (int)fminf(fmaxf(rintf(s1), 0.0f), fN1);
            int r1 = (int)fminf(fmaxf(rintf(s2), 0.0f), fN1);
            int c1 = (int)fminf(fmaxf(rintf(s3), 0.0f), fN1);
            float w0 = pa.w, w1 = pb.w;
            float xv0 = lx[c0];              // ds_read_b32 (lgkmcnt domain)
            float xv1 = lx[c1];

            // ---- zone B: prefetch next step's stream set (vmcnt domain) -----
            vfloat4 nzn, pan, pbn;
            bool have_next = (s + 1 < steps);
            if (have_next) {                 // uniform branch
                int qn = q + nthr;
                nzn = __builtin_nontemporal_load(&nb4[qn]);
                pan = pp[2 * qn];
                pbn = pp[2 * qn + 1];
                PIN4(nzn); PIN4(pan); PIN4(pbn);   // issue before commit
                q = qn;
            }

            // ---- zone C: commit — waits lgkmcnt only, vmcnt stays loaded ----
            float ctr0 = __fmul_rn(w0, xv0);
            float ctr1 = __fmul_rn(w1, xv1);
            bool lo0 = (r0 == 0), hi0 = (r0 == iN1);
            bool lo1 = (r1 == 0), hi1 = (r1 == iN1);
            if (!(lo0 | hi0)) atomicAdd(&ly[r0], ctr0);   // ~20% lanes active
            if (!(lo1 | hi1)) atomicAdd(&ly[r1], ctr1);
            acc0 = __fadd_rn(acc0, lo0 ? ctr0 : 0.0f);    // cndmask, branchless
            accE = __fadd_rn(accE, hi0 ? ctr0 : 0.0f);
            acc0 = __fadd_rn(acc0, lo1 ? ctr1 : 0.0f);
            accE = __fadd_rn(accE, hi1 ? ctr1 : 0.0f);

            if (have_next) { nz = nzn; pa = pan; pb = pbn; }
        }
    } else {
        // ---- generic / inline-params fallback (r6-verified masked body) ----
        const float2* nb = noise + (size_t)b * N;
        for (int t = tid; t < N; t += nthr) {
            float4 p;
            if (INLINE_PARAMS) {
                float2 pm = pmeans[t];
                float scale = (float)(N - 1);
                p.x = __fmul_rn(__fdiv_rn(1.0f, __fadd_rn(1.0f, expf(-pm.x))), scale);
                p.y = __fmul_rn(__fdiv_rn(1.0f, __fadd_rn(1.0f, expf(-pm.y))), scale);
                float z  = __fadd_rn(psigmas[t], SIGMA_BOOST);
                float sp = __fadd_rn(fmaxf(z, 0.0f), log1pf(expf(-fabsf(z))));
                p.z = __fmul_rn(__fadd_rn(sp, EPSILON), (float)N);
                p.w = pvalues[t];
            } else {
                p = params[t];
            }
            float2 nz = nb[t];
            float s0 = __fadd_rn(p.x, __fmul_rn(p.z, nz.x));
            float s1 = __fadd_rn(p.y, __fmul_rn(p.z, nz.y));
            int row = (int)fminf(fmaxf(rintf(s0), 0.0f), fN1);
            int col = (int)fminf(fmaxf(rintf(s1), 0.0f), fN1);
            float xv = xb[col];
            float ctr = __fmul_rn(p.w, xv);
            bool lo = (row == 0);
            bool hi = (row == iN1);
            if (!(lo | hi)) atomicAdd(&ly[row], ctr);
            acc0 = __fadd_rn(acc0, lo ? ctr : 0.0f);
            accE = __fadd_rn(accE, hi ? ctr : 0.0f);
        }
    }

    // fold register accumulators: wave shfl-reduce, one atomic per wave
    for (int off = 32; off > 0; off >>= 1) {
        acc0 = __fadd_rn(acc0, __shfl_down(acc0, off, 64));
        accE = __fadd_rn(accE, __shfl_down(accE, off, 64));
    }
    if ((tid & 63) == 0) {
        atomicAdd(&ly[0], acc0);
        atomicAdd(&ly[iN1], accE);
    }
    __syncthreads();

    // coalesced nontemporal write-out of the full row (y is never re-read)
    const vfloat4* lv4 = (const vfloat4*)ly;
    vfloat4* yb4 = (vfloat4*)(y + (size_t)b * N);
    for (int i = tid; i < n4; i += nthr)
        __builtin_nontemporal_store(lv4[i], &yb4[i]);
}

extern "C" void kernel_launch(void* const* d_in, const int* in_sizes, int n_in,
                              void* d_out, int out_size, void* d_ws, size_t ws_size,
                              hipStream_t stream) {
    const float*  x       = (const float*)d_in[0];
    const float2* noise   = (const float2*)d_in[1];
    const float2* pmeans  = (const float2*)d_in[2];
    const float*  psigmas = (const float*)d_in[3];
    const float*  pvalues = (const float*)d_in[4];
    float* y = (float*)d_out;

    const int N = in_sizes[3];          // psigmas is (N,)
    const int B = in_sizes[0] / N;      // x is (B,N)

    const size_t params_bytes = (size_t)N * sizeof(float4);
    const bool use_ws = (ws_size >= params_bytes) && (d_ws != nullptr);

    const int block = 1024;
    const size_t lds_min  = (size_t)N * sizeof(float);       // 64 KB: ly only
    const size_t lds_fast = 2 * lds_min;                     // 128 KB: ly + lx

    // fast-path shape gate (must mirror the kernel's `fast` condition)
    const bool shape_ok = ((N >> 1) % block == 0) && ((N >> 1) / block >= 2) &&
                          ((N & 3) == 0) && lds_fast <= 160 * 1024;

    if (use_ws) {
        bool fast_ok = shape_ok;
        if (fast_ok) {
            // dynamic LDS >64KB needs the opt-in attribute (verified r3/r4)
            hipError_t e = hipFuncSetAttribute(
                reinterpret_cast<const void*>(&contract_kernel<false>),
                hipFuncAttributeMaxDynamicSharedMemorySize, (int)lds_fast);
            fast_ok = (e == hipSuccess);
        }
        float4* params = (float4*)d_ws;
        params_kernel<<<(N + 255) / 256, 256, 0, stream>>>(pmeans, psigmas,
                                                           pvalues, params, N);
        contract_kernel<false><<<B, block,
                                 fast_ok ? lds_fast : lds_min, stream>>>(
            x, noise, params, nullptr, nullptr, nullptr, y, N);
    } else {
        contract_kernel<true><<<B, block, lds_min, stream>>>(
            x, noise, nullptr, pmeans, psigmas, pvalues, y, N);
    }
}